// Round 3
// baseline (347.468 us; speedup 1.0000x reference)
//
#include <hip/hip_runtime.h>
#include <hip/hip_bf16.h>
#include <stdint.h>

typedef __attribute__((ext_vector_type(8))) short s8v;   // 8 bf16 = K32 MFMA A/B frag
typedef __attribute__((ext_vector_type(4))) short s4v;   // 4 bf16 = K16 MFMA A/B frag
typedef __attribute__((ext_vector_type(4))) float f4v;   // MFMA C/D frag

#define NE   128
#define NT   2048
#define DIN  128
#define DH   512
#define DOUT 128

#define MFMA32(a,b,c) __builtin_amdgcn_mfma_f32_16x16x32_bf16(a,b,c,0,0,0)
// gfx90a-era builtin, valid on gfx950 (v_mfma_f32_16x16x16_bf16, A/B = short4).
// NOTE: do NOT guard with __has_builtin — it returns false in the HOST pass
// and the fallback path is what broke round 2.
#define MFMA16(a,b,c) __builtin_amdgcn_mfma_f32_16x16x16bf16_1k(a,b,c,0,0,0)

// async global->LDS, 16B per lane; LDS dest must be wave-uniform base + lane*16
#define GLOAD16(g,l) __builtin_amdgcn_global_load_lds( \
    (const __attribute__((address_space(1))) void*)(g), \
    (__attribute__((address_space(3))) void*)(l), 16, 0, 0)

// counted vmcnt wait (T4): "memory" clobber pins all memory ops (GLOAD16,
// ds_read) on their side of the wait so the hardware count matches source order
#define WAIT_VM(N) asm volatile("s_waitcnt vmcnt(" #N ")" ::: "memory")
// raw barrier (no implicit vmcnt(0) drain, unlike __syncthreads)
#define BAR() do { asm volatile("" ::: "memory"); \
                   __builtin_amdgcn_s_barrier();  \
                   asm volatile("" ::: "memory"); } while (0)

__device__ __forceinline__ __hip_bfloat162 pk2(float a, float b) {
  float2 t; t.x = a; t.y = b;
  return __float22bfloat162_rn(t);
}

__device__ __forceinline__ s8v pack8(float4 a, float4 b) {
  union { s8v v; __hip_bfloat162 h[4]; } u;
  u.h[0] = pk2(a.x, a.y); u.h[1] = pk2(a.z, a.w);
  u.h[2] = pk2(b.x, b.y); u.h[3] = pk2(b.z, b.w);
  return u.v;
}

// gelu(x) = x * sigmoid(x*(1.5957691 + 0.07135481*x^2))  (tanh-form rewritten)
__device__ __forceinline__ float gelu_f(float x) {
  float x2 = x * x;
  float p  = __builtin_fmaf(x2, 0.07135481f, 1.5957691f);
  float e  = __expf(-x * p);
  return x * __builtin_amdgcn_rcpf(1.0f + e);
}

// ---------------- prep: pack W1 (fp32 [e][128 d][512 h]) into K32 A-frag order
// W1F layout: [e][ht 0..31][ks 0..3][lane 0..63][8 bf16]; frag value j =
// W1[e][d = ks*32 + (lane>>4)*8 + j][h = ht*16 + (lane&15)]
__global__ __launch_bounds__(256) void pack_w1(const float* __restrict__ W1,
                                               ushort* __restrict__ W1F) {
  const int e = blockIdx.x >> 4, t2 = blockIdx.x & 15;   // t2 covers htiles 2*t2, 2*t2+1
  __shared__ float T[128][36];                            // [d][h-local 0..31]
  const int tid = threadIdx.x;
  const int d = tid >> 1, half = tid & 1;
  const float* src = W1 + (size_t)e * (DIN * DH) + (size_t)d * DH + t2 * 32 + half * 16;
  float4 v0 = *(const float4*)src;
  float4 v1 = *(const float4*)(src + 4);
  float4 v2 = *(const float4*)(src + 8);
  float4 v3 = *(const float4*)(src + 12);
  float* trow = &T[d][half * 16];
  *(float4*)(trow + 0) = v0; *(float4*)(trow + 4)  = v1;
  *(float4*)(trow + 8) = v2; *(float4*)(trow + 12) = v3;
  __syncthreads();
  const int lane = tid & 63, ks = tid >> 6;
  const int q = lane >> 4, l16 = lane & 15;
#pragma unroll
  for (int hl = 0; hl < 2; ++hl) {
    float g[8];
#pragma unroll
    for (int j = 0; j < 8; ++j) g[j] = T[ks * 32 + q * 8 + j][hl * 16 + l16];
    float4 a; a.x = g[0]; a.y = g[1]; a.z = g[2]; a.w = g[3];
    float4 b; b.x = g[4]; b.y = g[5]; b.z = g[6]; b.w = g[7];
    *(s8v*)(W1F + ((((size_t)e * 32 + t2 * 2 + hl) * 4) + ks) * 512 + lane * 8) = pack8(a, b);
  }
}

// ---------------- prep: pack W2 (fp32 [e][512 h][128 o]) into K16 B-frag order
// W2F layout: [e][ht 0..31][ot 0..7][lane 0..63][4 bf16]; frag value j =
// W2[e][h = ht*16 + (lane>>4)*4 + j][o = ot*16 + (lane&15)]
__global__ __launch_bounds__(256) void pack_w2(const float* __restrict__ W2,
                                               ushort* __restrict__ W2F) {
  const int e = blockIdx.x >> 5, ht = blockIdx.x & 31;
  __shared__ float T[16][132];                            // [h-local][o]
  const int tid = threadIdx.x;
  const int h = tid >> 4, c16 = tid & 15;
  const float* src = W2 + (size_t)e * (DH * DOUT) + (size_t)(ht * 16 + h) * DOUT + c16 * 8;
  float4 v0 = *(const float4*)src;
  float4 v1 = *(const float4*)(src + 4);
  float* trow = &T[h][c16 * 8];
  *(float4*)(trow + 0) = v0; *(float4*)(trow + 4) = v1;
  __syncthreads();
  const int lane = tid & 63;
  const int q = lane >> 4, l16 = lane & 15;
#pragma unroll
  for (int i = 0; i < 2; ++i) {
    int ot = (tid >> 6) + i * 4;
    float g0 = T[4 * q + 0][ot * 16 + l16];
    float g1 = T[4 * q + 1][ot * 16 + l16];
    float g2 = T[4 * q + 2][ot * 16 + l16];
    float g3 = T[4 * q + 3][ot * 16 + l16];
    union { s4v v; __hip_bfloat162 h2[2]; } u;
    u.h2[0] = pk2(g0, g1); u.h2[1] = pk2(g2, g3);
    *(s4v*)(W2F + (((size_t)e * 32 + ht) * 8 + ot) * 256 + lane * 4) = u.v;
  }
}

// ---------------- fused main kernel ----------------
// Block = 128 tokens of one expert, 4 waves; wave w owns m-range [32w, 32w+32).
// X frags live in VGPRs for the whole block (loaded once, fp32->bf16 in-reg).
// Stage1 (K=32): Ht = W1 . X^T  -> D regs ARE the K16 A-frag after gelu+pack.
// Stage2 (K=16): out += gelu(H) . W2, B-frags from frag-packed LDS (linear,
// conflict-free).
// Weight pipeline (T3+T4): 3 LDS buffers, depth-2 prefetch, counted
// s_waitcnt vmcnt(8) + raw s_barrier per chunk — the vmcnt never drains to 0
// inside the loop, so prefetch loads stay in flight across barriers.
// T1: bijective XCD swizzle keeps each expert's 16 blocks (256 KB of packed
// weights) on one XCD's L2.
__global__ __launch_bounds__(256, 3) void moe_fused(
    const float* __restrict__ X, const ushort* __restrict__ W1F,
    const ushort* __restrict__ W2F, float* __restrict__ Out) {
  __shared__ __align__(16) ushort W1s[3][4096];  // chunk: 2 htiles x 4 ks x 512
  __shared__ __align__(16) ushort W2s[3][4096];  // chunk: 2 htiles x 8 ot x 256

  const int tid  = threadIdx.x;
  const int lane = tid & 63;
  const int wid  = tid >> 6;
  const int q    = lane >> 4;
  const int l16  = lane & 15;

  // XCD swizzle: grid 2048 = 8 XCDs x 256 blocks (round-robin assumption).
  // XCD x gets work ids [x*256, x*256+256) = experts [x*16, x*16+16), all tiles.
  const int bid  = blockIdx.x;
  const int wk   = ((bid & 7) << 8) | (bid >> 3);
  const int e    = wk >> 4;
  const int tile = wk & 15;

  const float* Xe  = X + ((size_t)e * NT + (size_t)tile * 128) * DIN;
  const ushort* W1e = W1F + (size_t)e * 65536;
  const ushort* W2e = W2F + (size_t)e * 65536;
  float* Oe = Out + ((size_t)e * NT + (size_t)tile * 128) * DOUT;

  // ---- load this wave's X fragments into registers (once) ----
  s8v xf[2][4];
#pragma unroll
  for (int mt = 0; mt < 2; ++mt) {
#pragma unroll
    for (int ks = 0; ks < 4; ++ks) {
      const float* p = Xe + (size_t)(wid * 32 + mt * 16 + l16) * DIN + ks * 32 + q * 8;
      float4 v0 = *(const float4*)p;
      float4 v1 = *(const float4*)(p + 4);
      xf[mt][ks] = pack8(v0, v1);
    }
  }

  const f4v zero4 = {0.0f, 0.0f, 0.0f, 0.0f};
  f4v oacc[2][8];
#pragma unroll
  for (int mt = 0; mt < 2; ++mt)
#pragma unroll
    for (int ot = 0; ot < 8; ++ot) oacc[mt][ot] = zero4;

  // issue 4 global_load_lds per thread for one chunk (2x W1 + 2x W2)
  auto stage = [&](int chunk, int b) {
    const ushort* g1 = W1e + chunk * 4096;
    const ushort* g2 = W2e + chunk * 4096;
#pragma unroll
    for (int i = 0; i < 2; ++i) {
      int u = i * 256 + tid;
      GLOAD16(g1 + u * 8, &W1s[b][u * 8]);
      GLOAD16(g2 + u * 8, &W2s[b][u * 8]);
    }
  };

  // keep the xf float4 loads ordered before the staged GLOADs so the vmcnt
  // bookkeeping in the loop counts only weight loads
  asm volatile("" ::: "memory");

  // ---- prologue: chunks 0,1 into bufs 0,1 (8 loads/thread in flight) ----
  stage(0, 0);
  stage(1, 1);

  int buf = 0;                       // buf == c % 3
  for (int c = 0; c < 16; ++c) {
    if (c < 14) {                    // depth-2 prefetch into the freed buffer
      int nb = buf + 2; if (nb >= 3) nb -= 3;
      stage(c + 2, nb);
    }
    // wait for chunk c's 4 loads (mine); chunks c+1, c+2 stay in flight
    if (c < 14)       { WAIT_VM(8); }
    else if (c == 14) { WAIT_VM(4); }
    else              { WAIT_VM(0); }
    BAR();   // everyone waited -> all waves' chunk-c LDS writes are visible

#pragma unroll
    for (int hl = 0; hl < 2; ++hl) {
      // stage 1: K=32 over d, one 16-h tile
      f4v hacc[2]; hacc[0] = zero4; hacc[1] = zero4;
      s8v af[4];
#pragma unroll
      for (int ks = 0; ks < 4; ++ks)
        af[ks] = *(const s8v*)&W1s[buf][(hl * 4 + ks) * 512 + lane * 8];
      __builtin_amdgcn_s_setprio(1);
#pragma unroll
      for (int ks = 0; ks < 4; ++ks) {
        hacc[0] = MFMA32(af[ks], xf[0][ks], hacc[0]);
        hacc[1] = MFMA32(af[ks], xf[1][ks], hacc[1]);
      }
      __builtin_amdgcn_s_setprio(0);
      // gelu + pack: D regs (m=l16, h=4q+r) == K16 A-frag (row=l16, k=4q+j)
      s4v a2[2];
#pragma unroll
      for (int mt = 0; mt < 2; ++mt) {
        union { s4v v; __hip_bfloat162 h2[2]; } u;
        u.h2[0] = pk2(gelu_f(hacc[mt][0]), gelu_f(hacc[mt][1]));
        u.h2[1] = pk2(gelu_f(hacc[mt][2]), gelu_f(hacc[mt][3]));
        a2[mt] = u.v;
      }
      // stage 2: K=16, 8 o-tiles
      s4v bfr[8];
#pragma unroll
      for (int ot = 0; ot < 8; ++ot)
        bfr[ot] = *(const s4v*)&W2s[buf][(hl * 8 + ot) * 256 + lane * 4];
      __builtin_amdgcn_s_setprio(1);
#pragma unroll
      for (int ot = 0; ot < 8; ++ot) {
        oacc[0][ot] = MFMA16(a2[0], bfr[ot], oacc[0][ot]);
        oacc[1][ot] = MFMA16(a2[1], bfr[ot], oacc[1][ot]);
      }
      __builtin_amdgcn_s_setprio(0);
    }

    BAR();   // all waves done reading buf before it is restaged next iter
    ++buf; if (buf == 3) buf = 0;
  }

  // ---- epilogue: D layout col=o=l16, row m = 4q + r ----
#pragma unroll
  for (int mt = 0; mt < 2; ++mt) {
    const int mb = wid * 32 + mt * 16 + 4 * q;
#pragma unroll
    for (int ot = 0; ot < 8; ++ot) {
      float* p = Oe + (size_t)mb * DOUT + ot * 16 + l16;
      p[0 * DOUT] = oacc[mt][ot][0];
      p[1 * DOUT] = oacc[mt][ot][1];
      p[2 * DOUT] = oacc[mt][ot][2];
      p[3 * DOUT] = oacc[mt][ot][3];
    }
  }
}

extern "C" void kernel_launch(void* const* d_in, const int* in_sizes, int n_in,
                              void* d_out, int out_size, void* d_ws, size_t ws_size,
                              hipStream_t stream) {
  const float* X  = (const float*)d_in[0];
  const float* W1 = (const float*)d_in[1];
  const float* W2 = (const float*)d_in[2];
  float* Out = (float*)d_out;

  ushort* W1F = (ushort*)d_ws;                             // 128 KB/expert = 16.8 MB
  ushort* W2F = (ushort*)d_ws + (size_t)NE * 65536;        // 128 KB/expert = 16.8 MB

  pack_w1<<<NE * 16, 256, 0, stream>>>(W1, W1F);
  pack_w2<<<NE * 32, 256, 0, stream>>>(W2, W2F);
  moe_fused<<<NE * (NT / 128), 256, 0, stream>>>(X, W1F, W2F, Out);
}